// Round 4
// baseline (1535.255 us; speedup 1.0000x reference)
//
#include <hip/hip_runtime.h>

#define NN 50000
#define NE 800000
#define DD 128

#define FIX_SCALE 16777216.0f                      // 2^24
#define NWELEM 16384                               // per weight matrix
#define GEMM_GRID ((NN + 127) / 128)               // 391

// bucket sort params
#define SHIFT2 7
#define BWID 128                                   // nodes per coarse bucket (1<<SHIFT2)
#define NBUCK ((NN + BWID - 1) / BWID)             // 391 coarse buckets
#define CAP2 2560                                  // slots per coarse bucket (mean 2048, +11 sigma)
#define NB1 500                                    // scatter/histogram blocks (NE/NB1 = 1600 exact)
#define EPB (NE / NB1)                             // 1600 edges per block, 16B-aligned
#define EQ4 (EPB / 4)                              // 400 quads per block
#define NBK_PAD 392                                // hist/offs row stride

typedef __attribute__((ext_vector_type(8))) short short8;
typedef __attribute__((ext_vector_type(4))) float floatx4;
typedef __attribute__((ext_vector_type(4))) _Float16 half4;
typedef __attribute__((ext_vector_type(8))) _Float16 half8;

// ---------------- bf16 split (truncation; err ~2^-16 rel) ----------------

__device__ __forceinline__ void split_trunc(float x, short& hi, short& lo) {
    unsigned uh = __float_as_uint(x) >> 16;
    hi = (short)uh;
    float r = x - __uint_as_float(uh << 16);
    lo = (short)(__float_as_uint(r) >> 16);
}

// ---------------- stage 1: per-block edge histogram (fused with W split) ----------------

__global__ __launch_bounds__(256) void init_hist(const int* __restrict__ col,
                                                 unsigned* __restrict__ hist,
                                                 const float* __restrict__ W1, const float* __restrict__ W2,
                                                 unsigned short* __restrict__ w1hi, unsigned short* __restrict__ w1lo,
                                                 unsigned short* __restrict__ w2hi, unsigned short* __restrict__ w2lo) {
    if (blockIdx.x < NB1) {
        __shared__ unsigned h[NBUCK];
        for (int k = threadIdx.x; k < NBUCK; k += 256) h[k] = 0u;
        __syncthreads();
        const int4* c4p = (const int4*)(col + blockIdx.x * EPB);
#pragma unroll
        for (int it = 0; it < 2; it++) {
            int q = it * 256 + (int)threadIdx.x;
            if (q < EQ4) {
                int4 c4 = c4p[q];
                atomicAdd(&h[c4.x >> SHIFT2], 1u);
                atomicAdd(&h[c4.y >> SHIFT2], 1u);
                atomicAdd(&h[c4.z >> SHIFT2], 1u);
                atomicAdd(&h[c4.w >> SHIFT2], 1u);
            }
        }
        __syncthreads();
        unsigned* hb = hist + (size_t)blockIdx.x * NBK_PAD;
        for (int k = threadIdx.x; k < NBUCK; k += 256) hb[k] = h[k];
    } else {
        int u = (blockIdx.x - NB1) * 256 + threadIdx.x;     // [0, 2*NWELEM)
        int which = u >> 14;
        int idx = u & (NWELEM - 1);
        int k = idx >> 7, n = idx & 127;
        const float* W = which ? W2 : W1;
        unsigned short* whi = which ? w2hi : w1hi;
        unsigned short* wlo = which ? w2lo : w1lo;
        short h, l;
        split_trunc(W[idx], h, l);
        whi[n * DD + k] = (unsigned short)h;
        wlo[n * DD + k] = (unsigned short)l;
    }
}

// ---------------- stage 2: per-bucket exclusive prefix over blocks ----------------
// One block per coarse bucket; 512 threads >= NB1. Hillis-Steele scan in LDS.
// offs_t TRANSPOSED: offs_t[b*NBK_PAD + k] so scatter blocks load coalesced.

__global__ __launch_bounds__(512) void bucket_prefix(const unsigned* __restrict__ hist,
                                                     unsigned* __restrict__ offs_t,
                                                     unsigned* __restrict__ bcur) {
    __shared__ unsigned sa[512], sb[512];
    int k = blockIdx.x;
    int t = threadIdx.x;
    unsigned v = (t < NB1) ? hist[(size_t)t * NBK_PAD + k] : 0u;
    sa[t] = v;
    __syncthreads();
    unsigned* src = sa;
    unsigned* dst = sb;
    for (int d = 1; d < 512; d <<= 1) {
        unsigned x = src[t] + (t >= d ? src[t - d] : 0u);
        dst[t] = x;
        __syncthreads();
        unsigned* tmp = src; src = dst; dst = tmp;
    }
    unsigned inc = src[t];
    if (t < NB1) offs_t[(size_t)t * NBK_PAD + k] = inc - v;  // exclusive, transposed
    if (t == 511) bcur[k] = inc;
}

// ---------------- GEMM core (device fn): out[m,128] (fp16) = (relu?)in @ W (*dis?) ----------------

template <bool RELU, bool SCALE, typename InT>
__device__ __forceinline__ void gemm_core(int bid, const InT* __restrict__ in,
                                          const unsigned short* __restrict__ whi,
                                          const unsigned short* __restrict__ wlo,
                                          const float* __restrict__ dis,
                                          _Float16* __restrict__ out) {
    int lane = threadIdx.x & 63;
    int wid = threadIdx.x >> 6;
    int cg = wid & 1;
    int rg = wid >> 1;
    int l16 = lane & 15;
    int quad = lane >> 4;
    int koff_base = quad * 8;

    short8 bhi[4][4], blo[4][4];
#pragma unroll
    for (int t = 0; t < 4; t++) {
        int n = cg * 64 + t * 16 + l16;
#pragma unroll
        for (int ks = 0; ks < 4; ks++) {
            int koff = ks * 32 + koff_base;
            bhi[t][ks] = *(const short8*)(whi + n * DD + koff);
            blo[t][ks] = *(const short8*)(wlo + n * DD + koff);
        }
    }

#pragma unroll
    for (int chunk = 0; chunk < 4; chunk++) {
        int base = bid * 128 + chunk * 32 + rg * 16;
        int m = base + l16;
        int mld = (m < NN) ? m : 0;
        const InT* xr = in + (size_t)mld * DD;

        short8 ahi[4], alo[4];
#pragma unroll
        for (int ks = 0; ks < 4; ks++) {
            int koff = ks * 32 + koff_base;
            float v[8];
            if constexpr (sizeof(InT) == 4) {
                float4 a0 = *(const float4*)(xr + koff);
                float4 a1 = *(const float4*)(xr + koff + 4);
                v[0] = a0.x; v[1] = a0.y; v[2] = a0.z; v[3] = a0.w;
                v[4] = a1.x; v[5] = a1.y; v[6] = a1.z; v[7] = a1.w;
            } else {
                half8 a = *(const half8*)(xr + koff);
#pragma unroll
                for (int j = 0; j < 8; j++) v[j] = (float)a[j];
            }
#pragma unroll
            for (int j = 0; j < 8; j++) {
                float xv = RELU ? fmaxf(v[j], 0.0f) : v[j];
                short h, l;
                split_trunc(xv, h, l);
                ahi[ks][j] = h;
                alo[ks][j] = l;
            }
        }

        floatx4 acc[4];
#pragma unroll
        for (int t = 0; t < 4; t++) acc[t] = (floatx4)(0.0f);

#pragma unroll
        for (int ks = 0; ks < 4; ks++) {
#pragma unroll
            for (int t = 0; t < 4; t++) {
                acc[t] = __builtin_amdgcn_mfma_f32_16x16x32_bf16(ahi[ks], bhi[t][ks], acc[t], 0, 0, 0);
                acc[t] = __builtin_amdgcn_mfma_f32_16x16x32_bf16(alo[ks], bhi[t][ks], acc[t], 0, 0, 0);
                acc[t] = __builtin_amdgcn_mfma_f32_16x16x32_bf16(ahi[ks], blo[t][ks], acc[t], 0, 0, 0);
            }
        }

#pragma unroll
        for (int r = 0; r < 4; r++) {
            int rowm = base + quad * 4 + r;
            if (rowm < NN) {
                float dsc = SCALE ? dis[rowm] : 1.0f;
                _Float16* o = out + (size_t)rowm * DD + cg * 64 + l16;
#pragma unroll
                for (int t = 0; t < 4; t++) o[t * 16] = (_Float16)(acc[t][r] * dsc);
            }
        }
    }
}

// ---------------- stage 3 scatter (device fn): single pass, deterministic bases ----------------

__device__ __forceinline__ void scatter_core(int bid, const int* __restrict__ row,
                                             const int* __restrict__ col,
                                             const float* __restrict__ ew,
                                             const unsigned* __restrict__ offs_t,
                                             uint2* __restrict__ staged) {
    __shared__ unsigned base1[NBUCK];               // absolute staged slot base for this block
    __shared__ unsigned cnt1[NBUCK];

    const unsigned* ob = offs_t + (size_t)bid * NBK_PAD;    // coalesced (transposed layout)
    for (int k = threadIdx.x; k < NBUCK; k += 256) {
        base1[k] = (unsigned)k * CAP2 + ob[k];
        cnt1[k] = 0u;
    }
    __syncthreads();

    int e0 = bid * EPB;
    const int4* c4p = (const int4*)(col + e0);
    const int4* r4p = (const int4*)(row + e0);
    const float4* w4p = (const float4*)(ew + e0);

#pragma unroll
    for (int it = 0; it < 2; it++) {
        int q = it * 256 + (int)threadIdx.x;
        if (q < EQ4) {
            int4 c4 = c4p[q];
            int4 r4 = r4p[q];
            float4 w4 = w4p[q];
            int cc[4] = {c4.x, c4.y, c4.z, c4.w};
            int rr[4] = {r4.x, r4.y, r4.z, r4.w};
            float wv[4] = {w4.x, w4.y, w4.z, w4.w};
#pragma unroll
            for (int j = 0; j < 4; j++) {
                int bk = cc[j] >> SHIFT2;
                unsigned r = base1[bk] + atomicAdd(&cnt1[bk], 1u);
                unsigned lim = (unsigned)bk * CAP2 + (CAP2 - 1);
                if (r > lim) r = lim;               // memory safety on (impossible) overflow
                uint2 p;
                p.x = (unsigned)rr[j] | ((unsigned)(cc[j] & (BWID - 1)) << 16);   // row|ln<<16 (NN<65536)
                p.y = __float_as_uint(wv[j]);
                staged[r] = p;
            }
        }
    }
}

// ---------------- FUSED: stage-3 scatter + gemm1 (h1 = x@W1, raw) ----------------

__global__ __launch_bounds__(256) void gemm1_scatter(const float* __restrict__ x,
                                                     const unsigned short* __restrict__ w1hi,
                                                     const unsigned short* __restrict__ w1lo,
                                                     _Float16* __restrict__ g,
                                                     const int* __restrict__ row,
                                                     const int* __restrict__ col,
                                                     const float* __restrict__ ew,
                                                     const unsigned* __restrict__ offs_t,
                                                     uint2* __restrict__ staged) {
    if (blockIdx.x < NB1) {
        scatter_core(blockIdx.x, row, col, ew, offs_t, staged);
    } else {
        gemm_core<false, false, float>(blockIdx.x - NB1, x, w1hi, w1lo, nullptr, g);
    }
}

// layer-2 GEMM wrapper: g2' = dis * (relu(out1) @ W2)
__global__ __launch_bounds__(256, 2) void gemm2(const _Float16* __restrict__ in,
                                                const unsigned short* __restrict__ whi,
                                                const unsigned short* __restrict__ wlo,
                                                const float* __restrict__ dis,
                                                _Float16* __restrict__ out) {
    gemm_core<true, true, _Float16>(blockIdx.x, in, whi, wlo, dis, out);
}

// ---------------- bucket_dis: per-bucket weight-sum -> dis, then g' = dis*h ----------------
// One block per bucket (~2048 edges). One 32-bit LDS atomic per edge.

__global__ __launch_bounds__(256) void bucket_dis(const unsigned* __restrict__ bcur,
                                                  const uint2* __restrict__ staged,
                                                  float* __restrict__ dis,
                                                  _Float16* __restrict__ g) {
    __shared__ unsigned wfix[BWID];
    __shared__ float disS[BWID];

    int b = blockIdx.x;
    int node0 = b << SHIFT2;
    int nn = min(BWID, NN - node0);

    if (threadIdx.x < BWID) wfix[threadIdx.x] = 0u;
    __syncthreads();

    int m = min((int)bcur[b], CAP2);
    const uint2* st = staged + (size_t)b * CAP2;

    for (int j = threadIdx.x; j < m; j += 256) {
        uint2 p = st[j];
        int ln = p.x >> 16;                         // 7 bits
        float w = __uint_as_float(p.y);
        atomicAdd(&wfix[ln], (unsigned)(w * FIX_SCALE + 0.5f));   // max ~64*2^24 < 2^32
    }
    __syncthreads();

    if (threadIdx.x < (unsigned)nn) {
        float deg = 1.0f + (float)wfix[threadIdx.x] * (1.0f / FIX_SCALE);  // +1 self-loop
        float d = rsqrtf(deg);
        disS[threadIdx.x] = d;
        dis[node0 + threadIdx.x] = d;
    }
    __syncthreads();

    half8* gb = (half8*)(g + (size_t)node0 * DD);
    for (int idx = threadIdx.x; idx < nn * 16; idx += 256) {
        float d = disS[idx >> 4];
        half8 hv = gb[idx];
#pragma unroll
        for (int jj = 0; jj < 8; jj++) hv[jj] = (_Float16)((float)hv[jj] * d);
        gb[idx] = hv;
    }
}

// ---------------- agg_bucket: per-bucket LDS accumulation (replaces epk + per-node agg) ------
// One block per bucket, 8 waves, 64KB f32 LDS acc. Per edge: broadcast packed edge,
// gather g'[row] (lane i -> dims i, i+64: 2-way bank-free), ds_add_f32 into acc[ln].
// out[i] = bias + dis_i * (sum_e w_e*g'[row_e] + g'[i]),  g' = dis*h.

template <typename OutT>
__global__ __launch_bounds__(512) void agg_bucket(const unsigned* __restrict__ bcur,
                                                  const uint2* __restrict__ staged,
                                                  const _Float16* __restrict__ g,
                                                  const float* __restrict__ dis,
                                                  const float* __restrict__ bias,
                                                  OutT* __restrict__ out) {
    __shared__ float acc[BWID * DD];                // 64 KB

    int b = blockIdx.x;
    int node0 = b << SHIFT2;
    int nn = min(BWID, NN - node0);

    float4 z4 = {0.0f, 0.0f, 0.0f, 0.0f};
    float4* a4 = (float4*)acc;
#pragma unroll
    for (int it = 0; it < BWID * DD / 4 / 512; it++) a4[it * 512 + threadIdx.x] = z4;
    __syncthreads();

    int m = min((int)bcur[b], CAP2);
    const uint2* st = staged + (size_t)b * CAP2;

    int wid = threadIdx.x >> 6;                     // 8 waves
    int lane = threadIdx.x & 63;

    // paired edges: wave wid owns pair indices wid, wid+8, ... (j = 2*pair)
    int j = wid * 2;
    for (; j + 1 < m; j += 16) {
        uint4 pq = *(const uint4*)(st + j);         // 2 edges, wave-uniform broadcast
        unsigned r0 = (pq.x & 0xFFFFu) << 7;
        unsigned l0 = (pq.x >> 16) << 7;
        float w0 = __uint_as_float(pq.y);
        unsigned r1 = (pq.z & 0xFFFFu) << 7;
        unsigned l1 = (pq.z >> 16) << 7;
        float w1 = __uint_as_float(pq.w);
        float v0a = (float)g[r0 + lane];
        float v0b = (float)g[r0 + 64 + lane];
        float v1a = (float)g[r1 + lane];
        float v1b = (float)g[r1 + 64 + lane];
        atomicAdd(&acc[l0 + lane],      w0 * v0a);
        atomicAdd(&acc[l0 + 64 + lane], w0 * v0b);
        atomicAdd(&acc[l1 + lane],      w1 * v1a);
        atomicAdd(&acc[l1 + 64 + lane], w1 * v1b);
    }
    if ((m & 1) && j == m - 1) {                    // unpaired last edge (its owner wave)
        uint2 p = st[m - 1];
        unsigned r0 = (p.x & 0xFFFFu) << 7;
        unsigned l0 = (p.x >> 16) << 7;
        float w0 = __uint_as_float(p.y);
        atomicAdd(&acc[l0 + lane],      w0 * (float)g[r0 + lane]);
        atomicAdd(&acc[l0 + 64 + lane], w0 * (float)g[r0 + 64 + lane]);
    }
    __syncthreads();

    // epilogue: out = bias + d * (acc + g'_self), coalesced float4/half4 rows
    for (int t = threadIdx.x; t < nn * 32; t += 512) {
        int ln = t >> 5, q = t & 31;
        int i = node0 + ln;
        float d = dis[i];
        float4 av = ((const float4*)(acc + ln * DD))[q];
        half4 gs = *(const half4*)(g + (size_t)i * DD + q * 4);
        float4 bb = ((const float4*)bias)[q];
        float o0 = bb.x + d * (av.x + (float)gs.x);
        float o1 = bb.y + d * (av.y + (float)gs.y);
        float o2 = bb.z + d * (av.z + (float)gs.z);
        float o3 = bb.w + d * (av.w + (float)gs.w);
        if constexpr (sizeof(OutT) == 2) {
            half4 o;
            o.x = (_Float16)o0; o.y = (_Float16)o1;
            o.z = (_Float16)o2; o.w = (_Float16)o3;
            *(half4*)(out + (size_t)i * DD + q * 4) = o;
        } else {
            float4 o;
            o.x = o0; o.y = o1; o.z = o2; o.w = o3;
            ((float4*)(out + (size_t)i * DD))[q] = o;
        }
    }
}

// ---------------- launch ----------------

extern "C" void kernel_launch(void* const* d_in, const int* in_sizes, int n_in,
                              void* d_out, int out_size, void* d_ws, size_t ws_size,
                              hipStream_t stream) {
    const float* x  = (const float*)d_in[0];
    const int*   ei = (const int*)d_in[1];
    const float* ew = (const float*)d_in[2];
    const float* W1 = (const float*)d_in[3];
    const float* b1 = (const float*)d_in[4];
    const float* W2 = (const float*)d_in[5];
    const float* b2 = (const float*)d_in[6];
    float* out = (float*)d_out;

    // workspace layout (4B words)
    float* ws      = (float*)d_ws;
    float* dis     = ws;                                        // [0, 50000)
    unsigned* bcur = (unsigned*)(ws + 50000);                   // NBUCK u32
    unsigned* hist = (unsigned*)(ws + 150000);                  // NB1*NBK_PAD = 196000 words
    unsigned* offs_t = (unsigned*)(ws + 400000);                // NB1*NBK_PAD = 196000 words (transposed)
    uint2* staged  = (uint2*)(ws + 900000);                     // NBUCK*CAP2 uint2 = 2,001,920 words
    _Float16* gbuf = (_Float16*)(ws + 7300000);                 // NN*DD fp16 = 3.2M words
    unsigned short* wt1hi = (unsigned short*)(ws + 10500000);   // 8192 words each
    unsigned short* wt1lo = (unsigned short*)(ws + 10508192);
    unsigned short* wt2hi = (unsigned short*)(ws + 10516384);
    unsigned short* wt2lo = (unsigned short*)(ws + 10524576);
    _Float16* out1 = (_Float16*)(ws + 10532768);                // NN*DD fp16 = 3.2M words

    const int* rowi = ei;
    const int* coli = ei + NE;

    // ---- 1: per-block histogram + split W1/W2 ----
    init_hist<<<NB1 + (2 * NWELEM) / 256, 256, 0, stream>>>(
        coli, hist, W1, W2, wt1hi, wt1lo, wt2hi, wt2lo);

    // ---- 2: per-bucket prefix over blocks -> deterministic run bases ----
    bucket_prefix<<<NBUCK, 512, 0, stream>>>(hist, offs_t, bcur);

    // ---- 3: FUSED single-pass edge scatter + gemm1 (h1 = x@W1, raw) ----
    gemm1_scatter<<<NB1 + GEMM_GRID, 256, 0, stream>>>(
        x, wt1hi, wt1lo, gbuf, rowi, coli, ew, offs_t, staged);

    // ---- 4: per-bucket dis + g1' = dis*h1 ----
    bucket_dis<<<NBUCK, 256, 0, stream>>>(bcur, staged, dis, gbuf);

    // ---- 5: out1 = b1 + dis*(edge_sum + g1')  (fp16) ----
    agg_bucket<_Float16><<<NBUCK, 512, 0, stream>>>(bcur, staged, gbuf, dis, b1, out1);

    // ---- 6: g2' = dis*(relu(out1)@W2)  (fp16) ----
    gemm2<<<GEMM_GRID, 256, 0, stream>>>(out1, wt2hi, wt2lo, dis, gbuf);

    // ---- 7: out = b2 + dis*(edge_sum + g2')  (f32) ----
    agg_bucket<float><<<NBUCK, 512, 0, stream>>>(bcur, staged, gbuf, dis, b2, out);
}

// Round 5
// 213.389 us; speedup vs baseline: 7.1946x; 7.1946x over previous
//
#include <hip/hip_runtime.h>

#define NN 50000
#define NE 800000
#define DD 128

#define FIX_SCALE 16777216.0f                      // 2^24
#define NWELEM 16384                               // per weight matrix
#define GEMM_GRID ((NN + 127) / 128)               // 391

// bucket sort params
#define SHIFT2 7
#define BWID 128                                   // nodes per coarse bucket (1<<SHIFT2)
#define NBUCK ((NN + BWID - 1) / BWID)             // 391 coarse buckets
#define CAP2 2560                                  // slots per coarse bucket (mean 2048, +11 sigma)
#define NB1 500                                    // scatter/histogram blocks (NE/NB1 = 1600 exact)
#define EPB (NE / NB1)                             // 1600 edges per block, 16B-aligned
#define EQ4 (EPB / 4)                              // 400 quads per block
#define NBK_PAD 392                                // hist/offs row stride

typedef __attribute__((ext_vector_type(8))) short short8;
typedef __attribute__((ext_vector_type(4))) float floatx4;
typedef __attribute__((ext_vector_type(2))) _Float16 half2v;
typedef __attribute__((ext_vector_type(4))) _Float16 half4;
typedef __attribute__((ext_vector_type(8))) _Float16 half8;

// ---------------- bf16 split (truncation; err ~2^-16 rel) ----------------

__device__ __forceinline__ void split_trunc(float x, short& hi, short& lo) {
    unsigned uh = __float_as_uint(x) >> 16;
    hi = (short)uh;
    float r = x - __uint_as_float(uh << 16);
    lo = (short)(__float_as_uint(r) >> 16);
}

// ---------------- stage 1: per-block edge histogram (fused with W split) ----------------

__global__ __launch_bounds__(256) void init_hist(const int* __restrict__ col,
                                                 unsigned* __restrict__ hist,
                                                 const float* __restrict__ W1, const float* __restrict__ W2,
                                                 unsigned short* __restrict__ w1hi, unsigned short* __restrict__ w1lo,
                                                 unsigned short* __restrict__ w2hi, unsigned short* __restrict__ w2lo) {
    if (blockIdx.x < NB1) {
        __shared__ unsigned h[NBUCK];
        for (int k = threadIdx.x; k < NBUCK; k += 256) h[k] = 0u;
        __syncthreads();
        const int4* c4p = (const int4*)(col + blockIdx.x * EPB);
#pragma unroll
        for (int it = 0; it < 2; it++) {
            int q = it * 256 + (int)threadIdx.x;
            if (q < EQ4) {
                int4 c4 = c4p[q];
                atomicAdd(&h[c4.x >> SHIFT2], 1u);
                atomicAdd(&h[c4.y >> SHIFT2], 1u);
                atomicAdd(&h[c4.z >> SHIFT2], 1u);
                atomicAdd(&h[c4.w >> SHIFT2], 1u);
            }
        }
        __syncthreads();
        unsigned* hb = hist + (size_t)blockIdx.x * NBK_PAD;
        for (int k = threadIdx.x; k < NBUCK; k += 256) hb[k] = h[k];
    } else {
        int u = (blockIdx.x - NB1) * 256 + threadIdx.x;     // [0, 2*NWELEM)
        int which = u >> 14;
        int idx = u & (NWELEM - 1);
        int k = idx >> 7, n = idx & 127;
        const float* W = which ? W2 : W1;
        unsigned short* whi = which ? w2hi : w1hi;
        unsigned short* wlo = which ? w2lo : w1lo;
        short h, l;
        split_trunc(W[idx], h, l);
        whi[n * DD + k] = (unsigned short)h;
        wlo[n * DD + k] = (unsigned short)l;
    }
}

// ---------------- stage 2: per-bucket exclusive prefix over blocks ----------------
// One block per coarse bucket; 512 threads >= NB1. Hillis-Steele scan in LDS.
// offs_t TRANSPOSED: offs_t[b*NBK_PAD + k] so scatter blocks load coalesced.

__global__ __launch_bounds__(512) void bucket_prefix(const unsigned* __restrict__ hist,
                                                     unsigned* __restrict__ offs_t,
                                                     unsigned* __restrict__ bcur) {
    __shared__ unsigned sa[512], sb[512];
    int k = blockIdx.x;
    int t = threadIdx.x;
    unsigned v = (t < NB1) ? hist[(size_t)t * NBK_PAD + k] : 0u;
    sa[t] = v;
    __syncthreads();
    unsigned* src = sa;
    unsigned* dst = sb;
    for (int d = 1; d < 512; d <<= 1) {
        unsigned x = src[t] + (t >= d ? src[t - d] : 0u);
        dst[t] = x;
        __syncthreads();
        unsigned* tmp = src; src = dst; dst = tmp;
    }
    unsigned inc = src[t];
    if (t < NB1) offs_t[(size_t)t * NBK_PAD + k] = inc - v;  // exclusive, transposed
    if (t == 511) bcur[k] = inc;
}

// ---------------- GEMM core (device fn): out[m,128] (fp16) = (relu?)in @ W (*dis?) ----------------

template <bool RELU, bool SCALE, typename InT>
__device__ __forceinline__ void gemm_core(int bid, const InT* __restrict__ in,
                                          const unsigned short* __restrict__ whi,
                                          const unsigned short* __restrict__ wlo,
                                          const float* __restrict__ dis,
                                          _Float16* __restrict__ out) {
    int lane = threadIdx.x & 63;
    int wid = threadIdx.x >> 6;
    int cg = wid & 1;
    int rg = wid >> 1;
    int l16 = lane & 15;
    int quad = lane >> 4;
    int koff_base = quad * 8;

    short8 bhi[4][4], blo[4][4];
#pragma unroll
    for (int t = 0; t < 4; t++) {
        int n = cg * 64 + t * 16 + l16;
#pragma unroll
        for (int ks = 0; ks < 4; ks++) {
            int koff = ks * 32 + koff_base;
            bhi[t][ks] = *(const short8*)(whi + n * DD + koff);
            blo[t][ks] = *(const short8*)(wlo + n * DD + koff);
        }
    }

#pragma unroll
    for (int chunk = 0; chunk < 4; chunk++) {
        int base = bid * 128 + chunk * 32 + rg * 16;
        int m = base + l16;
        int mld = (m < NN) ? m : 0;
        const InT* xr = in + (size_t)mld * DD;

        short8 ahi[4], alo[4];
#pragma unroll
        for (int ks = 0; ks < 4; ks++) {
            int koff = ks * 32 + koff_base;
            float v[8];
            if constexpr (sizeof(InT) == 4) {
                float4 a0 = *(const float4*)(xr + koff);
                float4 a1 = *(const float4*)(xr + koff + 4);
                v[0] = a0.x; v[1] = a0.y; v[2] = a0.z; v[3] = a0.w;
                v[4] = a1.x; v[5] = a1.y; v[6] = a1.z; v[7] = a1.w;
            } else {
                half8 a = *(const half8*)(xr + koff);
#pragma unroll
                for (int j = 0; j < 8; j++) v[j] = (float)a[j];
            }
#pragma unroll
            for (int j = 0; j < 8; j++) {
                float xv = RELU ? fmaxf(v[j], 0.0f) : v[j];
                short h, l;
                split_trunc(xv, h, l);
                ahi[ks][j] = h;
                alo[ks][j] = l;
            }
        }

        floatx4 acc[4];
#pragma unroll
        for (int t = 0; t < 4; t++) acc[t] = (floatx4)(0.0f);

#pragma unroll
        for (int ks = 0; ks < 4; ks++) {
#pragma unroll
            for (int t = 0; t < 4; t++) {
                acc[t] = __builtin_amdgcn_mfma_f32_16x16x32_bf16(ahi[ks], bhi[t][ks], acc[t], 0, 0, 0);
                acc[t] = __builtin_amdgcn_mfma_f32_16x16x32_bf16(alo[ks], bhi[t][ks], acc[t], 0, 0, 0);
                acc[t] = __builtin_amdgcn_mfma_f32_16x16x32_bf16(ahi[ks], blo[t][ks], acc[t], 0, 0, 0);
            }
        }

#pragma unroll
        for (int r = 0; r < 4; r++) {
            int rowm = base + quad * 4 + r;
            if (rowm < NN) {
                float dsc = SCALE ? dis[rowm] : 1.0f;
                _Float16* o = out + (size_t)rowm * DD + cg * 64 + l16;
#pragma unroll
                for (int t = 0; t < 4; t++) o[t * 16] = (_Float16)(acc[t][r] * dsc);
            }
        }
    }
}

// ---------------- stage 3 scatter (device fn): single pass, deterministic bases ----------------

__device__ __forceinline__ void scatter_core(int bid, const int* __restrict__ row,
                                             const int* __restrict__ col,
                                             const float* __restrict__ ew,
                                             const unsigned* __restrict__ offs_t,
                                             uint2* __restrict__ staged) {
    __shared__ unsigned base1[NBUCK];               // absolute staged slot base for this block
    __shared__ unsigned cnt1[NBUCK];

    const unsigned* ob = offs_t + (size_t)bid * NBK_PAD;    // coalesced (transposed layout)
    for (int k = threadIdx.x; k < NBUCK; k += 256) {
        base1[k] = (unsigned)k * CAP2 + ob[k];
        cnt1[k] = 0u;
    }
    __syncthreads();

    int e0 = bid * EPB;
    const int4* c4p = (const int4*)(col + e0);
    const int4* r4p = (const int4*)(row + e0);
    const float4* w4p = (const float4*)(ew + e0);

#pragma unroll
    for (int it = 0; it < 2; it++) {
        int q = it * 256 + (int)threadIdx.x;
        if (q < EQ4) {
            int4 c4 = c4p[q];
            int4 r4 = r4p[q];
            float4 w4 = w4p[q];
            int cc[4] = {c4.x, c4.y, c4.z, c4.w};
            int rr[4] = {r4.x, r4.y, r4.z, r4.w};
            float wv[4] = {w4.x, w4.y, w4.z, w4.w};
#pragma unroll
            for (int j = 0; j < 4; j++) {
                int bk = cc[j] >> SHIFT2;
                unsigned r = base1[bk] + atomicAdd(&cnt1[bk], 1u);
                unsigned lim = (unsigned)bk * CAP2 + (CAP2 - 1);
                if (r > lim) r = lim;               // memory safety on (impossible) overflow
                uint2 p;
                p.x = (unsigned)rr[j] | ((unsigned)(cc[j] & (BWID - 1)) << 16);   // row|ln<<16 (NN<65536)
                p.y = __float_as_uint(wv[j]);
                staged[r] = p;
            }
        }
    }
}

// ---------------- FUSED: stage-3 scatter + gemm1 (h1 = x@W1, raw) ----------------

__global__ __launch_bounds__(256) void gemm1_scatter(const float* __restrict__ x,
                                                     const unsigned short* __restrict__ w1hi,
                                                     const unsigned short* __restrict__ w1lo,
                                                     _Float16* __restrict__ g,
                                                     const int* __restrict__ row,
                                                     const int* __restrict__ col,
                                                     const float* __restrict__ ew,
                                                     const unsigned* __restrict__ offs_t,
                                                     uint2* __restrict__ staged) {
    if (blockIdx.x < NB1) {
        scatter_core(blockIdx.x, row, col, ew, offs_t, staged);
    } else {
        gemm_core<false, false, float>(blockIdx.x - NB1, x, w1hi, w1lo, nullptr, g);
    }
}

// layer-2 GEMM wrapper: g2' = dis * (relu(out1) @ W2)
__global__ __launch_bounds__(256, 2) void gemm2(const _Float16* __restrict__ in,
                                                const unsigned short* __restrict__ whi,
                                                const unsigned short* __restrict__ wlo,
                                                const float* __restrict__ dis,
                                                _Float16* __restrict__ out) {
    gemm_core<true, true, _Float16>(blockIdx.x, in, whi, wlo, dis, out);
}

// ---------------- bucket_dis: per-bucket weight-sum -> dis, then g' = dis*h ----------------
// One block per bucket (~2048 edges). One native u32 LDS atomic per edge.

__global__ __launch_bounds__(256) void bucket_dis(const unsigned* __restrict__ bcur,
                                                  const uint2* __restrict__ staged,
                                                  float* __restrict__ dis,
                                                  _Float16* __restrict__ g) {
    __shared__ unsigned wfix[BWID];
    __shared__ float disS[BWID];

    int b = blockIdx.x;
    int node0 = b << SHIFT2;
    int nn = min(BWID, NN - node0);

    if (threadIdx.x < BWID) wfix[threadIdx.x] = 0u;
    __syncthreads();

    int m = min((int)bcur[b], CAP2);
    const uint2* st = staged + (size_t)b * CAP2;

    for (int j = threadIdx.x; j < m; j += 256) {
        uint2 p = st[j];
        int ln = p.x >> 16;                         // 7 bits
        float w = __uint_as_float(p.y);
        atomicAdd(&wfix[ln], (unsigned)(w * FIX_SCALE + 0.5f));   // max ~64*2^24 < 2^32
    }
    __syncthreads();

    if (threadIdx.x < (unsigned)nn) {
        float deg = 1.0f + (float)wfix[threadIdx.x] * (1.0f / FIX_SCALE);  // +1 self-loop
        float d = rsqrtf(deg);
        disS[threadIdx.x] = d;
        dis[node0 + threadIdx.x] = d;
    }
    __syncthreads();

    half8* gb = (half8*)(g + (size_t)node0 * DD);
    for (int idx = threadIdx.x; idx < nn * 16; idx += 256) {
        float d = disS[idx >> 4];
        half8 hv = gb[idx];
#pragma unroll
        for (int jj = 0; jj < 8; jj++) hv[jj] = (_Float16)((float)hv[jj] * d);
        gb[idx] = hv;
    }
}

// ---------------- agg_sorted: per-bucket node-sorted aggregation, REGISTER accumulation ------
// One 1024-thread block per bucket. Edges LDS-sorted by node (native u32 atomics only),
// then wave w owns nodes ln = w, w+16, ...: walks its contiguous edge runs, gathering
// g'[row] as one half2/lane (256B row per edge) into 2 register accumulators. No fp atomics.
// out[i] = bias + dis_i * (sum_e w_e*g'[row_e] + g'[i]),  g' = dis*h.

template <typename OutT>
__global__ __launch_bounds__(1024) void agg_sorted(const unsigned* __restrict__ bcur,
                                                   const uint2* __restrict__ staged,
                                                   const _Float16* __restrict__ g,
                                                   const float* __restrict__ dis,
                                                   const float* __restrict__ bias,
                                                   OutT* __restrict__ out) {
    __shared__ uint2 sRAW[CAP2];                    // 20 KB raw copy
    __shared__ uint2 sED[CAP2];                     // 20 KB node-sorted
    __shared__ unsigned cnt[BWID];
    __shared__ unsigned cur[BWID];
    __shared__ unsigned off[BWID];
    __shared__ unsigned sc[BWID];

    int b = blockIdx.x;
    int node0 = b << SHIFT2;
    int nn = min(BWID, NN - node0);

    if (threadIdx.x < BWID) cnt[threadIdx.x] = 0u;
    __syncthreads();

    int m = min((int)bcur[b], CAP2);
    const uint2* st = staged + (size_t)b * CAP2;

    // phase A: copy to LDS + per-node count (native u32 LDS atomics)
    for (int j = threadIdx.x; j < m; j += 1024) {
        uint2 p = st[j];
        sRAW[j] = p;
        atomicAdd(&cnt[p.x >> 16], 1u);
    }
    __syncthreads();

    // phase B: 128-wide exclusive prefix (Hillis-Steele)
    if (threadIdx.x < BWID) sc[threadIdx.x] = cnt[threadIdx.x];
    __syncthreads();
    for (int d = 1; d < BWID; d <<= 1) {
        unsigned v = 0;
        if (threadIdx.x < BWID) {
            v = sc[threadIdx.x];
            if ((int)threadIdx.x >= d) v += sc[threadIdx.x - d];
        }
        __syncthreads();
        if (threadIdx.x < BWID) sc[threadIdx.x] = v;
        __syncthreads();
    }
    if (threadIdx.x < BWID) {
        off[threadIdx.x] = sc[threadIdx.x] - cnt[threadIdx.x];
        cur[threadIdx.x] = 0u;
    }
    __syncthreads();

    // phase C: bucket-sort edges by node into sED (pre-scale row -> row*DD)
    for (int j = threadIdx.x; j < m; j += 1024) {
        uint2 p = sRAW[j];
        int ln = p.x >> 16;
        unsigned r = off[ln] + atomicAdd(&cur[ln], 1u);
        uint2 q;
        q.x = (p.x & 0xFFFFu) << 7;
        q.y = p.y;
        sED[r] = q;
    }
    __syncthreads();

    // phase D: register accumulation, wave-owned nodes (no races, no atomics)
    int wid = threadIdx.x >> 6;                     // 16 waves
    int lane = threadIdx.x & 63;
    for (int ln = wid; ln < nn; ln += 16) {
        int s0 = (int)off[ln];
        int e0 = s0 + (int)cnt[ln];
        float a0 = 0.0f, a1 = 0.0f;
        int j = s0;
        for (; j + 3 < e0; j += 4) {
            uint2 p0 = sED[j], p1 = sED[j + 1], p2 = sED[j + 2], p3 = sED[j + 3];
            half2v v0 = *(const half2v*)(g + p0.x + 2 * lane);
            half2v v1 = *(const half2v*)(g + p1.x + 2 * lane);
            half2v v2 = *(const half2v*)(g + p2.x + 2 * lane);
            half2v v3 = *(const half2v*)(g + p3.x + 2 * lane);
            float w0 = __uint_as_float(p0.y), w1 = __uint_as_float(p1.y);
            float w2 = __uint_as_float(p2.y), w3 = __uint_as_float(p3.y);
            a0 = fmaf(w0, (float)v0.x, a0); a1 = fmaf(w0, (float)v0.y, a1);
            a0 = fmaf(w1, (float)v1.x, a0); a1 = fmaf(w1, (float)v1.y, a1);
            a0 = fmaf(w2, (float)v2.x, a0); a1 = fmaf(w2, (float)v2.y, a1);
            a0 = fmaf(w3, (float)v3.x, a0); a1 = fmaf(w3, (float)v3.y, a1);
        }
        for (; j < e0; ++j) {
            uint2 p0 = sED[j];
            half2v v0 = *(const half2v*)(g + p0.x + 2 * lane);
            float w0 = __uint_as_float(p0.y);
            a0 = fmaf(w0, (float)v0.x, a0); a1 = fmaf(w0, (float)v0.y, a1);
        }
        int i = node0 + ln;
        float d = dis[i];
        half2v gs = *(const half2v*)(g + (size_t)i * DD + 2 * lane);
        float2 bb = *(const float2*)(bias + 2 * lane);
        float o0 = bb.x + d * (a0 + (float)gs.x);
        float o1 = bb.y + d * (a1 + (float)gs.y);
        if constexpr (sizeof(OutT) == 2) {
            half2v o; o.x = (_Float16)o0; o.y = (_Float16)o1;
            *(half2v*)(out + (size_t)i * DD + 2 * lane) = o;
        } else {
            float2 o; o.x = o0; o.y = o1;
            *(float2*)(out + (size_t)i * DD + 2 * lane) = o;
        }
    }
}

// ---------------- launch ----------------

extern "C" void kernel_launch(void* const* d_in, const int* in_sizes, int n_in,
                              void* d_out, int out_size, void* d_ws, size_t ws_size,
                              hipStream_t stream) {
    const float* x  = (const float*)d_in[0];
    const int*   ei = (const int*)d_in[1];
    const float* ew = (const float*)d_in[2];
    const float* W1 = (const float*)d_in[3];
    const float* b1 = (const float*)d_in[4];
    const float* W2 = (const float*)d_in[5];
    const float* b2 = (const float*)d_in[6];
    float* out = (float*)d_out;

    // workspace layout (4B words)
    float* ws      = (float*)d_ws;
    float* dis     = ws;                                        // [0, 50000)
    unsigned* bcur = (unsigned*)(ws + 50000);                   // NBUCK u32
    unsigned* hist = (unsigned*)(ws + 150000);                  // NB1*NBK_PAD = 196000 words
    unsigned* offs_t = (unsigned*)(ws + 400000);                // NB1*NBK_PAD = 196000 words (transposed)
    uint2* staged  = (uint2*)(ws + 900000);                     // NBUCK*CAP2 uint2 = 2,001,920 words
    _Float16* gbuf = (_Float16*)(ws + 7300000);                 // NN*DD fp16 = 3.2M words
    unsigned short* wt1hi = (unsigned short*)(ws + 10500000);   // 8192 words each
    unsigned short* wt1lo = (unsigned short*)(ws + 10508192);
    unsigned short* wt2hi = (unsigned short*)(ws + 10516384);
    unsigned short* wt2lo = (unsigned short*)(ws + 10524576);
    _Float16* out1 = (_Float16*)(ws + 10532768);                // NN*DD fp16 = 3.2M words

    const int* rowi = ei;
    const int* coli = ei + NE;

    // ---- 1: per-block histogram + split W1/W2 ----
    init_hist<<<NB1 + (2 * NWELEM) / 256, 256, 0, stream>>>(
        coli, hist, W1, W2, wt1hi, wt1lo, wt2hi, wt2lo);

    // ---- 2: per-bucket prefix over blocks -> deterministic run bases ----
    bucket_prefix<<<NBUCK, 512, 0, stream>>>(hist, offs_t, bcur);

    // ---- 3: FUSED single-pass edge scatter + gemm1 (h1 = x@W1, raw) ----
    gemm1_scatter<<<NB1 + GEMM_GRID, 256, 0, stream>>>(
        x, wt1hi, wt1lo, gbuf, rowi, coli, ew, offs_t, staged);

    // ---- 4: per-bucket dis + g1' = dis*h1 ----
    bucket_dis<<<NBUCK, 256, 0, stream>>>(bcur, staged, dis, gbuf);

    // ---- 5: out1 = b1 + dis*(edge_sum + g1')  (fp16) ----
    agg_sorted<_Float16><<<NBUCK, 1024, 0, stream>>>(bcur, staged, gbuf, dis, b1, out1);

    // ---- 6: g2' = dis*(relu(out1)@W2)  (fp16) ----
    gemm2<<<GEMM_GRID, 256, 0, stream>>>(out1, wt2hi, wt2lo, dis, gbuf);

    // ---- 7: out = b2 + dis*(edge_sum + g2')  (f32) ----
    agg_sorted<float><<<NBUCK, 1024, 0, stream>>>(bcur, staged, gbuf, dis, b2, out);
}